// Round 12
// baseline (360.023 us; speedup 1.0000x reference)
//
#include <hip/hip_runtime.h>
#include <hip/hip_bf16.h>

typedef __attribute__((ext_vector_type(8))) short s16x8;
typedef __attribute__((ext_vector_type(4))) float f32x4;
typedef unsigned short u16;
typedef unsigned int u32;

constexpr int NN = 50000;
constexpr int NE = 600000;

__device__ inline u16 f2b(float x) {
    __hip_bfloat16 h = __float2bfloat16(x);
    return *(u16*)&h;
}

__device__ inline s16x8 pack8(float4 a, float4 b) {
    s16x8 r;
    r[0] = (short)f2b(a.x); r[1] = (short)f2b(a.y);
    r[2] = (short)f2b(a.z); r[3] = (short)f2b(a.w);
    r[4] = (short)f2b(b.x); r[5] = (short)f2b(b.y);
    r[6] = (short)f2b(b.z); r[7] = (short)f2b(b.w);
    return r;
}

// ---------------- misc small kernels ----------------

__global__ void k_zero(int* __restrict__ p, int n) {
    int i = blockIdx.x * 256 + threadIdx.x;
    if (i < n) p[i] = 0;
}

__global__ void k_padvf(const float* __restrict__ vf, float* __restrict__ vp) {
    int i = blockIdx.x * 256 + threadIdx.x;
    if (i < NN * 32) {
        int n = i >> 5, c = i & 31;
        vp[i] = c < 16 ? vf[n * 16 + c] : 0.f;
    }
}

// B_packed element store: fragment-ordered weights.
// element (col, k) -> u16 index ((chunk*8 + jj)*64 + lane)*8 + (k&7)
//   chunk=k>>5, jj=col>>4, lane=(col&15) | (((k>>3)&3)<<4)
__device__ inline void bp_store(u16* Bp, int col, int k, float v) {
    int chunk = k >> 5, jj = col >> 4;
    int lane = (col & 15) | (((k >> 3) & 3) << 4);
    Bp[(size_t)(((chunk * 8 + jj) * 64 + lane) * 8 + (k & 7))] = f2b(v);
}

// input-layer fused weights, packed: k<768: (fc2_w @ relu_w_bot); 768..783: (fc1_w @ relu_w_top); 784..799: 0
__global__ void k_win(const float* __restrict__ fc1w, const float* __restrict__ fc2w,
                      const float* __restrict__ reluw, u16* __restrict__ Bp) {
    int c = threadIdx.x;   // output col 0..127
    int k = blockIdx.x;    // 0..799
    float s = 0.f;
    if (k < 768) {
        for (int j = 0; j < 128; ++j) s += fc2w[k * 128 + j] * reluw[(128 + j) * 128 + c];
    } else if (k < 784) {
        int kk = k - 768;
        for (int j = 0; j < 128; ++j) s += fc1w[kk * 128 + j] * reluw[j * 128 + c];
    }
    bp_store(Bp, c, k, s);
}

__global__ void k_bcomb(const float* __restrict__ fc1b, const float* __restrict__ fc2b,
                        const float* __restrict__ relub, const float* __restrict__ reluw,
                        float* __restrict__ bcomb) {
    int c = threadIdx.x;
    float s = relub[c];
    for (int j = 0; j < 128; ++j) {
        s += fc1b[j] * reluw[j * 128 + c];
        s += fc2b[j] * reluw[(128 + j) * 128 + c];
    }
    bcomb[c] = s;
}

// RGCN stacked weights [wrel(3x128x128); wroot(128x128)], packed
__global__ void k_wrg(const float* __restrict__ wrel, const float* __restrict__ wroot,
                      u16* __restrict__ Bp) {
    int c = threadIdx.x;   // output col
    int s = blockIdx.x;    // stacked k-row 0..511
    float v = (s < 384) ? wrel[(size_t)s * 128 + c] : wroot[(size_t)(s - 384) * 128 + c];
    bp_store(Bp, c, s, v);
}

// ---------------- CSR build ----------------

__global__ void k_hist(const int* __restrict__ ei, const int* __restrict__ et,
                       int* __restrict__ deg_node, int* __restrict__ deg_rel) {
    int e = blockIdx.x * 256 + threadIdx.x;
    if (e >= NE) return;
    int dst = ei[NE + e];
    int r = et[e];
    atomicAdd(&deg_node[dst], 1);
    atomicAdd(&deg_rel[r * NN + dst], 1);
}

__global__ void k_alloc(const int* __restrict__ deg_node, int* __restrict__ baseoff,
                        int* __restrict__ counter) {
    int i = blockIdx.x * 256 + threadIdx.x;
    int lane = threadIdx.x & 63;
    int d = (i < NN) ? deg_node[i] : 0;
    int scan = d;
    for (int off = 1; off < 64; off <<= 1) {
        int t = __shfl_up(scan, off, 64);
        if (lane >= off) scan += t;
    }
    int total = __shfl(scan, 63, 64);
    int wbase = 0;
    if (lane == 63) wbase = atomicAdd(counter, total);
    wbase = __shfl(wbase, 63, 64);
    if (i < NN) baseoff[i] = wbase + scan - d;
}

__global__ void k_norm(const int* __restrict__ deg_rel, float* __restrict__ normf) {
    int i = blockIdx.x * 256 + threadIdx.x;
    if (i < 3 * NN) normf[i] = 1.0f / (float)max(deg_rel[i], 1);
}

__global__ void k_fill(const int* __restrict__ ei, const int* __restrict__ et,
                       const int* __restrict__ baseoff, int* __restrict__ cursor,
                       int* __restrict__ elist) {
    int e = blockIdx.x * 256 + threadIdx.x;
    if (e >= NE) return;
    int dst = ei[NE + e];
    int src = ei[e];
    int r = et[e];
    int pos = atomicAdd(&cursor[dst], 1);
    elist[baseoff[dst] + pos] = src | (r << 20);
}

// ---------------- aggregation (gather over CSR): 1 wave per node ----------------

__global__ __launch_bounds__(64) void k_agg(const u16* __restrict__ x, u16* __restrict__ A,
                                            const int* __restrict__ elist,
                                            const int* __restrict__ baseoff,
                                            const int* __restrict__ deg_node,
                                            const float* __restrict__ normf) {
    int n = blockIdx.x;
    int lane = threadIdx.x;
    float a0x = 0.f, a0y = 0.f, a1x = 0.f, a1y = 0.f, a2x = 0.f, a2y = 0.f;
    int nb = deg_node[n];
    int b0 = baseoff[n];
    for (int i = 0; i < nb; ++i) {
        int p = elist[b0 + i];
        int src = p & 0xFFFFF;
        int r = p >> 20;
        u32 pair = *(const u32*)&x[(size_t)src * 128 + lane * 2];
        float vx = __uint_as_float((pair & 0xFFFFu) << 16);
        float vy = __uint_as_float((pair >> 16) << 16);
        if (r == 0)      { a0x += vx; a0y += vy; }
        else if (r == 1) { a1x += vx; a1y += vy; }
        else             { a2x += vx; a2y += vy; }
    }
    float n0 = normf[n], n1 = normf[NN + n], n2 = normf[2 * NN + n];
    u32* Ao = (u32*)&A[(size_t)n * 384];
    Ao[lane]        = (u32)f2b(a0x * n0) | ((u32)f2b(a0y * n0) << 16);
    Ao[64 + lane]   = (u32)f2b(a1x * n1) | ((u32)f2b(a1y * n1) << 16);
    Ao[128 + lane]  = (u32)f2b(a2x * n2) | ((u32)f2b(a2y * n2) << 16);
}

// ---------------- GEMM: zero-barrier, zero-staging ----------------
// Wave = 16 output rows x 128 cols. Per k32-step: 1-2 A-frag loads (16-segment
// semi-coalesced, lanes {l,l+16,l+32,l+48} read contiguous 64/128B of row l&15),
// 8 B-frag loads (fully coalesced 1KB, same addresses in every wave -> L1
// broadcast; B pre-packed in fragment order by k_win/k_wrg), 8 MFMA.
// No __syncthreads anywhere: compiler software-pipelines with counted waitcnts.
// Epilogue: wave-private LDS bounce -> 16B/lane coalesced stores.

template <typename TA, int K1T, int K2T, bool LRELU>
__device__ __forceinline__ void gemm_body(const TA* __restrict__ A1, int lda1,
                                          const TA* __restrict__ A2, int lda2,
                                          const u16* __restrict__ Bp,
                                          const float* __restrict__ bias,
                                          u16* __restrict__ out) {
    constexpr int KT = K1T + K2T;
    __shared__ u16 epi[4][2176];   // per-wave 16 rows x 136 u16 pitch
    const int tid = threadIdx.x;
    const int w = tid >> 6, l = tid & 63;
    const int lr = l & 15, lq = l >> 4;
    const int wrow = (blockIdx.x * 4 + w) * 16;
    if (wrow >= NN) return;        // NN % 16 == 0: whole surplus waves exit

    const TA* a1p = A1 + (size_t)(wrow + lr) * lda1 + lq * 8;
    const TA* a2p = A2 + (size_t)(wrow + lr) * lda2 + lq * 8;
    const u16* bp = Bp + l * 8;    // frag-chunk stride = 512 u16

    f32x4 acc[8] = {};

    auto loadA = [&](int kt) -> s16x8 {
        if (kt < K1T) {
            if constexpr (sizeof(TA) == 4) {
                float4 f0 = *(const float4*)(a1p + kt * 32);
                float4 f1 = *(const float4*)(a1p + kt * 32 + 4);
                return pack8(f0, f1);
            } else {
                return *(const s16x8*)(a1p + kt * 32);
            }
        } else {
            int k2 = (kt - K1T) * 32;
            if constexpr (sizeof(TA) == 4) {
                float4 f0 = *(const float4*)(a2p + k2);
                float4 f1 = *(const float4*)(a2p + k2 + 4);
                return pack8(f0, f1);
            } else {
                return *(const s16x8*)(a2p + k2);
            }
        }
    };

    s16x8 a_cur = loadA(0);
#pragma unroll
    for (int kt = 0; kt < KT; ++kt) {
        s16x8 a_nxt;
        if (kt + 1 < KT) a_nxt = loadA(kt + 1);
#pragma unroll
        for (int j = 0; j < 8; ++j) {
            s16x8 bf = *(const s16x8*)(bp + (size_t)(kt * 8 + j) * 512);
            acc[j] = __builtin_amdgcn_mfma_f32_16x16x32_bf16(a_cur, bf, acc[j], 0, 0, 0);
        }
        a_cur = a_nxt;
    }

    // epilogue: C mapping (16x16): row=(l>>4)*4+q, col=16j+(l&15)
    u16* ep = epi[w];
#pragma unroll
    for (int j = 0; j < 8; ++j) {
        float bj = bias[j * 16 + lr];
#pragma unroll
        for (int q = 0; q < 4; ++q) {
            float v = acc[j][q] + bj;
            if (LRELU) v = v > 0.f ? v : 0.01f * v;
            ep[(lq * 4 + q) * 136 + j * 16 + lr] = f2b(v);
        }
    }
    // wave-private readback (in-order LDS per wave; compiler inserts lgkmcnt)
#pragma unroll
    for (int t = 0; t < 4; ++t) {
        int row = 4 * t + (l >> 4);
        int ch = l & 15;
        s16x8 vrow = *(const s16x8*)&ep[row * 136 + ch * 8];
        *(s16x8*)&out[(size_t)(wrow + row) * 128 + ch * 8] = vrow;
    }
}

__global__ __launch_bounds__(256, 2) void k_gin(const float* __restrict__ A1, int lda1,
                                                const float* __restrict__ A2, int lda2,
                                                const u16* __restrict__ Bp,
                                                const float* __restrict__ bias,
                                                u16* __restrict__ out) {
    gemm_body<float, 24, 1, true>(A1, lda1, A2, lda2, Bp, bias, out);
}
__global__ __launch_bounds__(256, 2) void k_gr1(const u16* __restrict__ A1, int lda1,
                                                const u16* __restrict__ A2, int lda2,
                                                const u16* __restrict__ Bp,
                                                const float* __restrict__ bias,
                                                u16* __restrict__ out) {
    gemm_body<u16, 12, 4, false>(A1, lda1, A2, lda2, Bp, bias, out);
}
__global__ __launch_bounds__(256, 2) void k_gr2(const u16* __restrict__ A1, int lda1,
                                                const u16* __restrict__ A2, int lda2,
                                                const u16* __restrict__ Bp,
                                                const float* __restrict__ bias,
                                                u16* __restrict__ out) {
    gemm_body<u16, 12, 4, false>(A1, lda1, A2, lda2, Bp, bias, out);
}

// ---------------- final gather + classifier ----------------

__global__ __launch_bounds__(256) void k_out(const u16* __restrict__ h, const int* __restrict__ idx,
                                             const float* __restrict__ fc3w,
                                             const float* __restrict__ fc3b,
                                             float* __restrict__ out, int M) {
    int w = threadIdx.x >> 6;
    int lane = threadIdx.x & 63;
    int row = blockIdx.x * 4 + w;
    if (row >= M) return;
    int n = idx[row];
    u32 pair = *(const u32*)&h[(size_t)n * 128 + lane * 2];
    float v0 = __uint_as_float((pair & 0xFFFFu) << 16);
    float v1 = __uint_as_float((pair >> 16) << 16);
    float4 wv = *(const float4*)&fc3w[lane * 4];
    float s0 = v0 * wv.x + v1 * wv.z;
    float s1 = v0 * wv.y + v1 * wv.w;
    for (int off = 32; off >= 1; off >>= 1) {
        s0 += __shfl_xor(s0, off, 64);
        s1 += __shfl_xor(s1, off, 64);
    }
    if (lane == 0) {
        out[row * 2] = s0 + fc3b[0];
        out[row * 2 + 1] = s1 + fc3b[1];
    }
}

// ---------------- launch ----------------

extern "C" void kernel_launch(void* const* d_in, const int* in_sizes, int n_in,
                              void* d_out, int out_size, void* d_ws, size_t ws_size,
                              hipStream_t stream) {
    const float* vf    = (const float*)d_in[0];
    const float* tf    = (const float*)d_in[1];
    const float* fc1w  = (const float*)d_in[2];
    const float* fc1b  = (const float*)d_in[3];
    const float* fc2w  = (const float*)d_in[4];
    const float* fc2b  = (const float*)d_in[5];
    const float* reluw = (const float*)d_in[6];
    const float* relub = (const float*)d_in[7];
    const float* w1rel = (const float*)d_in[8];
    const float* w1root= (const float*)d_in[9];
    const float* b1    = (const float*)d_in[10];
    const float* w2rel = (const float*)d_in[11];
    const float* w2root= (const float*)d_in[12];
    const float* b2    = (const float*)d_in[13];
    const float* fc3w  = (const float*)d_in[14];
    const float* fc3b  = (const float*)d_in[15];
    const int* ei      = (const int*)d_in[16];
    const int* et      = (const int*)d_in[17];
    const int* idx     = (const int*)d_in[18];
    float* out = (float*)d_out;

    char* W = (char*)d_ws;
    const size_t OFF_BPIN  = 0;         // 25*8*64*16 = 204800
    const size_t OFF_BP1   = 204800;    // 16*8*64*16 = 131072
    const size_t OFF_BP2   = 335872;    // 131072
    const size_t OFF_BCOMB = 466944;    // 512
    const size_t OFF_DEGN  = 467456;
    const size_t OFF_CUR   = 667456;
    const size_t OFF_DEGR  = 867456;
    const size_t OFF_CNT   = 1467456;
    const size_t OFF_BASE  = 1467712;
    const size_t OFF_NORM  = 1667712;
    const size_t OFF_ELIST = 2267712;
    const size_t OFF_A     = 4667712;
    const size_t OFF_H0    = 43067712;
    const size_t OFF_H1    = 55867712;
    const size_t OFF_H2    = 68667712;
    const size_t OFF_VFPAD = 81467712;

    u16* BpIn   = (u16*)(W + OFF_BPIN);
    u16* Bp1    = (u16*)(W + OFF_BP1);
    u16* Bp2    = (u16*)(W + OFF_BP2);
    float* bcomb= (float*)(W + OFF_BCOMB);
    int* degn   = (int*)(W + OFF_DEGN);
    int* cur    = (int*)(W + OFF_CUR);
    int* degr   = (int*)(W + OFF_DEGR);
    int* cnt    = (int*)(W + OFF_CNT);
    int* base   = (int*)(W + OFF_BASE);
    float* normf= (float*)(W + OFF_NORM);
    int* elist  = (int*)(W + OFF_ELIST);
    u16* Abuf   = (u16*)(W + OFF_A);
    u16* h0     = (u16*)(W + OFF_H0);
    u16* h1     = (u16*)(W + OFF_H1);
    u16* h2     = (u16*)(W + OFF_H2);
    float* vfp  = (float*)(W + OFF_VFPAD);

    const int GRID_GEMM = (NN / 16 + 3) / 4;   // 782 blocks x 4 waves, 16 rows/wave

    k_zero<<<(250001 + 255) / 256, 256, 0, stream>>>(degn, 250001);
    k_padvf<<<(NN * 32 + 255) / 256, 256, 0, stream>>>(vf, vfp);

    k_win<<<800, 128, 0, stream>>>(fc1w, fc2w, reluw, BpIn);
    k_bcomb<<<1, 128, 0, stream>>>(fc1b, fc2b, relub, reluw, bcomb);
    k_wrg<<<512, 128, 0, stream>>>(w1rel, w1root, Bp1);
    k_wrg<<<512, 128, 0, stream>>>(w2rel, w2root, Bp2);

    k_gin<<<GRID_GEMM, 256, 0, stream>>>(tf, 768, vfp, 32, BpIn, bcomb, h0);

    k_hist<<<(NE + 255) / 256, 256, 0, stream>>>(ei, et, degn, degr);
    k_alloc<<<(NN + 255) / 256, 256, 0, stream>>>(degn, base, cnt);
    k_norm<<<(3 * NN + 255) / 256, 256, 0, stream>>>(degr, normf);
    k_fill<<<(NE + 255) / 256, 256, 0, stream>>>(ei, et, base, cur, elist);

    k_agg<<<NN, 64, 0, stream>>>(h0, Abuf, elist, base, degn, normf);
    k_gr1<<<GRID_GEMM, 256, 0, stream>>>(Abuf, 384, h0, 128, Bp1, b1, h1);

    k_agg<<<NN, 64, 0, stream>>>(h1, Abuf, elist, base, degn, normf);
    k_gr2<<<GRID_GEMM, 256, 0, stream>>>(Abuf, 384, h1, 128, Bp2, b2, h2);

    k_out<<<(10000 + 3) / 4, 256, 0, stream>>>(h2, idx, fc3w, fc3b, out, 10000);
}

// Round 13
// 320.330 us; speedup vs baseline: 1.1239x; 1.1239x over previous
//
#include <hip/hip_runtime.h>
#include <hip/hip_bf16.h>

typedef __attribute__((ext_vector_type(8))) short s16x8;
typedef __attribute__((ext_vector_type(4))) float f32x4;
typedef unsigned short u16;
typedef unsigned int u32;

constexpr int NN = 50000;
constexpr int NE = 600000;

__device__ inline u16 f2b(float x) {
    __hip_bfloat16 h = __float2bfloat16(x);
    return *(u16*)&h;
}

__device__ inline s16x8 pack8(float4 a, float4 b) {
    s16x8 r;
    r[0] = (short)f2b(a.x); r[1] = (short)f2b(a.y);
    r[2] = (short)f2b(a.z); r[3] = (short)f2b(a.w);
    r[4] = (short)f2b(b.x); r[5] = (short)f2b(b.y);
    r[6] = (short)f2b(b.z); r[7] = (short)f2b(b.w);
    return r;
}

// async global->LDS DMA, 16B per lane: LDS dst = wave-uniform base + lane*16.
__device__ inline void gl_lds16(const void* gptr, void* lptr) {
    __builtin_amdgcn_global_load_lds(
        (const __attribute__((address_space(1))) char*)gptr,
        (__attribute__((address_space(3))) char*)lptr, 16, 0, 0);
}

template <int N> __device__ inline void vmwait() {
    asm volatile("s_waitcnt vmcnt(%0)" :: "n"(N) : "memory");
}
__device__ inline void barrier_nodrains() {
    __builtin_amdgcn_sched_barrier(0);
    __builtin_amdgcn_s_barrier();
    __builtin_amdgcn_sched_barrier(0);
}

// ---------------- misc small kernels ----------------

__global__ void k_zero(int* __restrict__ p, int n) {
    int i = blockIdx.x * 256 + threadIdx.x;
    if (i < n) p[i] = 0;
}

__global__ void k_padvf(const float* __restrict__ vf, float* __restrict__ vp) {
    int i = blockIdx.x * 256 + threadIdx.x;
    if (i < NN * 32) {
        int n = i >> 5, c = i & 31;
        vp[i] = c < 16 ? vf[n * 16 + c] : 0.f;
    }
}

// WTin[c][k], k<768: (fc2_w @ relu_w_bot)^T ; 768..783: (fc1_w @ relu_w_top)^T ; 784..799: 0
__global__ void k_win(const float* __restrict__ fc1w, const float* __restrict__ fc2w,
                      const float* __restrict__ reluw, u16* __restrict__ WTin) {
    int c = threadIdx.x;
    int k = blockIdx.x;
    float s = 0.f;
    if (k < 768) {
        for (int j = 0; j < 128; ++j) s += fc2w[k * 128 + j] * reluw[(128 + j) * 128 + c];
    } else if (k < 784) {
        int kk = k - 768;
        for (int j = 0; j < 128; ++j) s += fc1w[kk * 128 + j] * reluw[j * 128 + c];
    }
    WTin[c * 800 + k] = f2b(s);
}

__global__ void k_bcomb(const float* __restrict__ fc1b, const float* __restrict__ fc2b,
                        const float* __restrict__ relub, const float* __restrict__ reluw,
                        float* __restrict__ bcomb) {
    int c = threadIdx.x;
    float s = relub[c];
    for (int j = 0; j < 128; ++j) {
        s += fc1b[j] * reluw[j * 128 + c];
        s += fc2b[j] * reluw[(128 + j) * 128 + c];
    }
    bcomb[c] = s;
}

// WT[c][s] = stacked [wrel(3x128x128); wroot(128x128)] transposed, bf16
__global__ void k_wrg(const float* __restrict__ wrel, const float* __restrict__ wroot,
                      u16* __restrict__ WT) {
    int c = threadIdx.x;
    int s = blockIdx.x;
    float v = (s < 384) ? wrel[(size_t)s * 128 + c] : wroot[(size_t)(s - 384) * 128 + c];
    WT[c * 512 + s] = f2b(v);
}

// ---------------- CSR build ----------------

__global__ void k_hist(const int* __restrict__ ei, const int* __restrict__ et,
                       int* __restrict__ deg_node, int* __restrict__ deg_rel) {
    int e = blockIdx.x * 256 + threadIdx.x;
    if (e >= NE) return;
    int dst = ei[NE + e];
    int r = et[e];
    atomicAdd(&deg_node[dst], 1);
    atomicAdd(&deg_rel[r * NN + dst], 1);
}

__global__ void k_alloc(const int* __restrict__ deg_node, int* __restrict__ baseoff,
                        int* __restrict__ counter) {
    int i = blockIdx.x * 256 + threadIdx.x;
    int lane = threadIdx.x & 63;
    int d = (i < NN) ? deg_node[i] : 0;
    int scan = d;
    for (int off = 1; off < 64; off <<= 1) {
        int t = __shfl_up(scan, off, 64);
        if (lane >= off) scan += t;
    }
    int total = __shfl(scan, 63, 64);
    int wbase = 0;
    if (lane == 63) wbase = atomicAdd(counter, total);
    wbase = __shfl(wbase, 63, 64);
    if (i < NN) baseoff[i] = wbase + scan - d;
}

__global__ void k_norm(const int* __restrict__ deg_rel, float* __restrict__ normf) {
    int i = blockIdx.x * 256 + threadIdx.x;
    if (i < 3 * NN) normf[i] = 1.0f / (float)max(deg_rel[i], 1);
}

__global__ void k_fill(const int* __restrict__ ei, const int* __restrict__ et,
                       const int* __restrict__ baseoff, int* __restrict__ cursor,
                       int* __restrict__ elist) {
    int e = blockIdx.x * 256 + threadIdx.x;
    if (e >= NE) return;
    int dst = ei[NE + e];
    int src = ei[e];
    int r = et[e];
    int pos = atomicAdd(&cursor[dst], 1);
    elist[baseoff[dst] + pos] = src | (r << 20);
}

// ---------------- aggregation: 4 nodes/block (1 wave each), MLP-batched gathers ----------------
// Per wave: load up to 64 edge descriptors in ONE coalesced load, broadcast via
// __shfl; gather 8 source rows per batch into registers (8 independent 256B row
// loads in flight) then accumulate. Kills the old serial elist->gather chain.

__global__ __launch_bounds__(256) void k_agg(const u16* __restrict__ x, u16* __restrict__ A,
                                             const int* __restrict__ elist,
                                             const int* __restrict__ baseoff,
                                             const int* __restrict__ deg_node,
                                             const float* __restrict__ normf) {
    int n = blockIdx.x * 4 + (threadIdx.x >> 6);
    if (n >= NN) return;
    int lane = threadIdx.x & 63;
    float a0x = 0.f, a0y = 0.f, a1x = 0.f, a1y = 0.f, a2x = 0.f, a2y = 0.f;
    int nb = deg_node[n];
    int b0 = baseoff[n];
    for (int c0 = 0; c0 < nb; c0 += 64) {
        int cc = min(64, nb - c0);
        int p = (c0 + lane < nb) ? elist[b0 + c0 + lane] : 0;
        for (int bb = 0; bb < cc; bb += 8) {
            int m = min(8, cc - bb);
            u32 pair[8];
            int rr[8];
#pragma unroll
            for (int k = 0; k < 8; ++k) {
                if (k < m) {
                    int pj = __shfl(p, bb + k, 64);
                    rr[k] = pj >> 20;
                    pair[k] = *(const u32*)&x[(size_t)(pj & 0xFFFFF) * 128 + lane * 2];
                }
            }
#pragma unroll
            for (int k = 0; k < 8; ++k) {
                if (k < m) {
                    float vx = __uint_as_float((pair[k] & 0xFFFFu) << 16);
                    float vy = __uint_as_float((pair[k] >> 16) << 16);
                    if (rr[k] == 0)      { a0x += vx; a0y += vy; }
                    else if (rr[k] == 1) { a1x += vx; a1y += vy; }
                    else                 { a2x += vx; a2y += vy; }
                }
            }
        }
    }
    float n0 = normf[n], n1 = normf[NN + n], n2 = normf[2 * NN + n];
    u32* Ao = (u32*)&A[(size_t)n * 384];
    Ao[lane]        = (u32)f2b(a0x * n0) | ((u32)f2b(a0y * n0) << 16);
    Ao[64 + lane]   = (u32)f2b(a1x * n1) | ((u32)f2b(a1y * n1) << 16);
    Ao[128 + lane]  = (u32)f2b(a2x * n2) | ((u32)f2b(a2y * n2) << 16);
}

// ---------------- GEMM body (round-11, best measured): BM=64, 3 LDS buffers,
// prefetch depth 2, counted vmcnt at no-drain barriers ----------------

template <typename TA, int K1T, int K2T, bool LRELU>
__device__ __forceinline__ void gemm_body(const TA* __restrict__ A1, int lda1,
                                          const TA* __restrict__ A2, int lda2,
                                          const u16* __restrict__ WT, int ldwt,
                                          const float* __restrict__ bias,
                                          u16* __restrict__ out, int N) {
    constexpr int KT = K1T + K2T;
    constexpr int ABYTES = 64 * 32 * (int)sizeof(TA);
    constexpr int TILEB = ABYTES + 8192;
    constexpr int OPW = (sizeof(TA) == 4) ? 4 : 3;   // DMA instrs per wave per stage
    __shared__ alignas(128) char lds[3][TILEB];

    const int tid = threadIdx.x;
    const int m0 = blockIdx.x * 64;
    const int w = tid >> 6, lane = tid & 63;
    const int wr = w >> 1, wc = w & 1;
    const int lq = lane >> 4, lr = lane & 15;

    auto stage = [&](int j) {
        char* base = lds[j % 3];
        int kt = j;
        if constexpr (sizeof(TA) == 4) {
#pragma unroll
            for (int jj = 0; jj < 2; ++jj) {
                int row = w * 16 + jj * 8 + (lane >> 3);
                int s = lane & 7;
                int chunk = s ^ (row & 7);
                int rg = min(m0 + row, N - 1);
                const float* g;
                if (kt < K1T) g = (const float*)A1 + (size_t)rg * lda1 + kt * 32 + chunk * 4;
                else          g = (const float*)A2 + (size_t)rg * lda2 + (kt - K1T) * 32 + chunk * 4;
                gl_lds16(g, base + w * 2048 + jj * 1024);
            }
        } else {
            int row = w * 16 + (lane >> 2);
            int s = lane & 3;
            int chunk = s ^ ((row >> 1) & 3);
            int rg = min(m0 + row, N - 1);
            const u16* g;
            if (kt < K1T) g = (const u16*)A1 + (size_t)rg * lda1 + kt * 32 + chunk * 8;
            else          g = (const u16*)A2 + (size_t)rg * lda2 + (kt - K1T) * 32 + chunk * 8;
            gl_lds16(g, base + w * 1024);
        }
#pragma unroll
        for (int jj = 0; jj < 2; ++jj) {
            int col = w * 32 + jj * 16 + (lane >> 2);
            int s = lane & 3;
            int chunk = s ^ ((col >> 1) & 3);
            const u16* g = WT + (size_t)col * ldwt + kt * 32 + chunk * 8;
            gl_lds16(g, base + ABYTES + w * 2048 + jj * 1024);
        }
    };

    f32x4 acc[2][4] = {};

    auto compute = [&](int j) {
        char* base = lds[j % 3];
        s16x8 af[2];
#pragma unroll
        for (int i = 0; i < 2; ++i) {
            int row = wr * 32 + i * 16 + lr;
            if constexpr (sizeof(TA) == 4) {
                int m = row & 7;
                float4 f0 = *(const float4*)(base + row * 128 + (((2 * lq) ^ m) * 16));
                float4 f1 = *(const float4*)(base + row * 128 + (((2 * lq + 1) ^ m) * 16));
                af[i] = pack8(f0, f1);
            } else {
                int sl = lq ^ ((row >> 1) & 3);
                af[i] = *(const s16x8*)(base + row * 64 + sl * 16);
            }
        }
#pragma unroll
        for (int j4 = 0; j4 < 4; ++j4) {
            int col = wc * 64 + j4 * 16 + lr;
            int sl = lq ^ ((col >> 1) & 3);
            s16x8 bf = *(const s16x8*)(base + ABYTES + col * 64 + sl * 16);
#pragma unroll
            for (int i = 0; i < 2; ++i)
                acc[i][j4] = __builtin_amdgcn_mfma_f32_16x16x32_bf16(af[i], bf, acc[i][j4], 0, 0, 0);
        }
    };

    stage(0); stage(1);
#pragma unroll 1
    for (int j = 0; j < KT - 1; ++j) {
        vmwait<OPW>();
        barrier_nodrains();
        if (j + 2 < KT) stage(j + 2);
        compute(j);
    }
    vmwait<0>();
    barrier_nodrains();
    compute(KT - 1);

#pragma unroll
    for (int i = 0; i < 2; ++i) {
#pragma unroll
        for (int q = 0; q < 4; ++q) {
            int grow = m0 + wr * 32 + i * 16 + lq * 4 + q;
            if (grow < N) {
#pragma unroll
                for (int j = 0; j < 4; ++j) {
                    int col = wc * 64 + j * 16 + lr;
                    float v = acc[i][j][q] + bias[col];
                    if (LRELU) v = v > 0.f ? v : 0.01f * v;
                    out[(size_t)grow * 128 + col] = f2b(v);
                }
            }
        }
    }
}

__global__ __launch_bounds__(256) void k_gemm_in(const float* __restrict__ A1, int lda1,
                                                 const float* __restrict__ A2, int lda2,
                                                 const u16* __restrict__ WT, int ldwt,
                                                 const float* __restrict__ bias,
                                                 u16* __restrict__ out, int N) {
    gemm_body<float, 24, 1, true>(A1, lda1, A2, lda2, WT, ldwt, bias, out, N);
}
__global__ __launch_bounds__(256) void k_gemm_r1(const u16* __restrict__ A1, int lda1,
                                                 const u16* __restrict__ A2, int lda2,
                                                 const u16* __restrict__ WT, int ldwt,
                                                 const float* __restrict__ bias,
                                                 u16* __restrict__ out, int N) {
    gemm_body<u16, 12, 4, false>(A1, lda1, A2, lda2, WT, ldwt, bias, out, N);
}
__global__ __launch_bounds__(256) void k_gemm_r2(const u16* __restrict__ A1, int lda1,
                                                 const u16* __restrict__ A2, int lda2,
                                                 const u16* __restrict__ WT, int ldwt,
                                                 const float* __restrict__ bias,
                                                 u16* __restrict__ out, int N) {
    gemm_body<u16, 12, 4, false>(A1, lda1, A2, lda2, WT, ldwt, bias, out, N);
}

// ---------------- final gather + classifier ----------------

__global__ __launch_bounds__(256) void k_out(const u16* __restrict__ h, const int* __restrict__ idx,
                                             const float* __restrict__ fc3w,
                                             const float* __restrict__ fc3b,
                                             float* __restrict__ out, int M) {
    int w = threadIdx.x >> 6;
    int lane = threadIdx.x & 63;
    int row = blockIdx.x * 4 + w;
    if (row >= M) return;
    int n = idx[row];
    u32 pair = *(const u32*)&h[(size_t)n * 128 + lane * 2];
    float v0 = __uint_as_float((pair & 0xFFFFu) << 16);
    float v1 = __uint_as_float((pair >> 16) << 16);
    float4 wv = *(const float4*)&fc3w[lane * 4];
    float s0 = v0 * wv.x + v1 * wv.z;
    float s1 = v0 * wv.y + v1 * wv.w;
    for (int off = 32; off >= 1; off >>= 1) {
        s0 += __shfl_xor(s0, off, 64);
        s1 += __shfl_xor(s1, off, 64);
    }
    if (lane == 0) {
        out[row * 2] = s0 + fc3b[0];
        out[row * 2 + 1] = s1 + fc3b[1];
    }
}

// ---------------- launch ----------------

extern "C" void kernel_launch(void* const* d_in, const int* in_sizes, int n_in,
                              void* d_out, int out_size, void* d_ws, size_t ws_size,
                              hipStream_t stream) {
    const float* vf    = (const float*)d_in[0];
    const float* tf    = (const float*)d_in[1];
    const float* fc1w  = (const float*)d_in[2];
    const float* fc1b  = (const float*)d_in[3];
    const float* fc2w  = (const float*)d_in[4];
    const float* fc2b  = (const float*)d_in[5];
    const float* reluw = (const float*)d_in[6];
    const float* relub = (const float*)d_in[7];
    const float* w1rel = (const float*)d_in[8];
    const float* w1root= (const float*)d_in[9];
    const float* b1    = (const float*)d_in[10];
    const float* w2rel = (const float*)d_in[11];
    const float* w2root= (const float*)d_in[12];
    const float* b2    = (const float*)d_in[13];
    const float* fc3w  = (const float*)d_in[14];
    const float* fc3b  = (const float*)d_in[15];
    const int* ei      = (const int*)d_in[16];
    const int* et      = (const int*)d_in[17];
    const int* idx     = (const int*)d_in[18];
    float* out = (float*)d_out;

    char* W = (char*)d_ws;
    const size_t OFF_WTIN  = 0;
    const size_t OFF_WT1   = 204800;
    const size_t OFF_WT2   = 335872;
    const size_t OFF_BCOMB = 466944;
    const size_t OFF_DEGN  = 467456;
    const size_t OFF_CUR   = 667456;
    const size_t OFF_DEGR  = 867456;
    const size_t OFF_CNT   = 1467456;
    const size_t OFF_BASE  = 1467712;
    const size_t OFF_NORM  = 1667712;
    const size_t OFF_ELIST = 2267712;
    const size_t OFF_A     = 4667712;
    const size_t OFF_H0    = 43067712;
    const size_t OFF_H1    = 55867712;
    const size_t OFF_H2    = 68667712;
    const size_t OFF_VFPAD = 81467712;

    u16* WTin   = (u16*)(W + OFF_WTIN);
    u16* WT1    = (u16*)(W + OFF_WT1);
    u16* WT2    = (u16*)(W + OFF_WT2);
    float* bcomb= (float*)(W + OFF_BCOMB);
    int* degn   = (int*)(W + OFF_DEGN);
    int* cur    = (int*)(W + OFF_CUR);
    int* degr   = (int*)(W + OFF_DEGR);
    int* cnt    = (int*)(W + OFF_CNT);
    int* base   = (int*)(W + OFF_BASE);
    float* normf= (float*)(W + OFF_NORM);
    int* elist  = (int*)(W + OFF_ELIST);
    u16* Abuf   = (u16*)(W + OFF_A);
    u16* h0     = (u16*)(W + OFF_H0);
    u16* h1     = (u16*)(W + OFF_H1);
    u16* h2     = (u16*)(W + OFF_H2);
    float* vfp  = (float*)(W + OFF_VFPAD);

    const int GRID_GEMM = (NN + 63) / 64;   // 782 blocks
    const int GRID_AGG  = (NN + 3) / 4;     // 12500 blocks x 4 waves

    k_zero<<<(250001 + 255) / 256, 256, 0, stream>>>(degn, 250001);
    k_padvf<<<(NN * 32 + 255) / 256, 256, 0, stream>>>(vf, vfp);

    k_win<<<800, 128, 0, stream>>>(fc1w, fc2w, reluw, WTin);
    k_bcomb<<<1, 128, 0, stream>>>(fc1b, fc2b, relub, reluw, bcomb);
    k_wrg<<<512, 128, 0, stream>>>(w1rel, w1root, WT1);
    k_wrg<<<512, 128, 0, stream>>>(w2rel, w2root, WT2);

    k_gemm_in<<<GRID_GEMM, 256, 0, stream>>>(tf, 768, vfp, 32, WTin, 800, bcomb, h0, NN);

    k_hist<<<(NE + 255) / 256, 256, 0, stream>>>(ei, et, degn, degr);
    k_alloc<<<(NN + 255) / 256, 256, 0, stream>>>(degn, base, cnt);
    k_norm<<<(3 * NN + 255) / 256, 256, 0, stream>>>(degr, normf);
    k_fill<<<(NE + 255) / 256, 256, 0, stream>>>(ei, et, base, cur, elist);

    k_agg<<<GRID_AGG, 256, 0, stream>>>(h0, Abuf, elist, base, degn, normf);
    k_gemm_r1<<<GRID_GEMM, 256, 0, stream>>>(Abuf, 384, h0, 128, WT1, 512, b1, h1, NN);

    k_agg<<<GRID_AGG, 256, 0, stream>>>(h1, Abuf, elist, base, degn, normf);
    k_gemm_r2<<<GRID_GEMM, 256, 0, stream>>>(Abuf, 384, h1, 128, WT2, 512, b2, h2, NN);

    k_out<<<(10000 + 3) / 4, 256, 0, stream>>>(h2, idx, fc3w, fc3b, out, 10000);
}

// Round 14
// 246.550 us; speedup vs baseline: 1.4602x; 1.2993x over previous
//
#include <hip/hip_runtime.h>
#include <hip/hip_bf16.h>

typedef __attribute__((ext_vector_type(8))) short s16x8;
typedef __attribute__((ext_vector_type(4))) float f32x4;
typedef unsigned short u16;
typedef unsigned int u32;

constexpr int NN = 50000;
constexpr int NE = 600000;
constexpr int NIDX = 10000;

__device__ inline u16 f2b(float x) {
    __hip_bfloat16 h = __float2bfloat16(x);
    return *(u16*)&h;
}

__device__ inline s16x8 pack8(float4 a, float4 b) {
    s16x8 r;
    r[0] = (short)f2b(a.x); r[1] = (short)f2b(a.y);
    r[2] = (short)f2b(a.z); r[3] = (short)f2b(a.w);
    r[4] = (short)f2b(b.x); r[5] = (short)f2b(b.y);
    r[6] = (short)f2b(b.z); r[7] = (short)f2b(b.w);
    return r;
}

// async global->LDS DMA, 16B per lane: LDS dst = wave-uniform base + lane*16.
__device__ inline void gl_lds16(const void* gptr, void* lptr) {
    __builtin_amdgcn_global_load_lds(
        (const __attribute__((address_space(1))) char*)gptr,
        (__attribute__((address_space(3))) char*)lptr, 16, 0, 0);
}

template <int N> __device__ inline void vmwait() {
    asm volatile("s_waitcnt vmcnt(%0)" :: "n"(N) : "memory");
}
__device__ inline void barrier_nodrains() {
    __builtin_amdgcn_sched_barrier(0);
    __builtin_amdgcn_s_barrier();
    __builtin_amdgcn_sched_barrier(0);
}

// ---------------- fused setup: padvf | win | bcomb | wrg1 | wrg2 | zeros | mark-zero ----------------

__global__ void k_setup(const float* __restrict__ vf,
                        const float* __restrict__ fc1w, const float* __restrict__ fc2w,
                        const float* __restrict__ reluw,
                        const float* __restrict__ fc1b, const float* __restrict__ fc2b,
                        const float* __restrict__ relub,
                        const float* __restrict__ w1rel, const float* __restrict__ w1root,
                        const float* __restrict__ w2rel, const float* __restrict__ w2root,
                        float* __restrict__ vfp, u16* __restrict__ WTin,
                        float* __restrict__ bcomb, u16* __restrict__ WT1, u16* __restrict__ WT2,
                        int* __restrict__ zero_region, int* __restrict__ mark) {
    int b = blockIdx.x, t = threadIdx.x;
    if (b < 6250) {                              // padvf: NN*32 = 1.6M
        int i = b * 256 + t;
        int n = i >> 5, c = i & 31;
        vfp[i] = c < 16 ? vf[n * 16 + c] : 0.f;
    } else if (b < 7050) {                       // win: k = b-6250 in [0,800)
        if (t < 128) {
            int k = b - 6250, c = t;
            float s = 0.f;
            if (k < 768) {
                for (int j = 0; j < 128; ++j) s += fc2w[k * 128 + j] * reluw[(128 + j) * 128 + c];
            } else if (k < 784) {
                int kk = k - 768;
                for (int j = 0; j < 128; ++j) s += fc1w[kk * 128 + j] * reluw[j * 128 + c];
            }
            WTin[c * 800 + k] = f2b(s);
        }
    } else if (b == 7050) {                      // bcomb
        if (t < 128) {
            int c = t;
            float s = relub[c];
            for (int j = 0; j < 128; ++j) {
                s += fc1b[j] * reluw[j * 128 + c];
                s += fc2b[j] * reluw[(128 + j) * 128 + c];
            }
            bcomb[c] = s;
        }
    } else if (b < 7563) {                       // wrg1: s = b-7051 in [0,512)
        if (t < 128) {
            int s = b - 7051, c = t;
            float v = (s < 384) ? w1rel[(size_t)s * 128 + c] : w1root[(size_t)(s - 384) * 128 + c];
            WT1[c * 512 + s] = f2b(v);
        }
    } else if (b < 8075) {                       // wrg2
        if (t < 128) {
            int s = b - 7563, c = t;
            float v = (s < 384) ? w2rel[(size_t)s * 128 + c] : w2root[(size_t)(s - 384) * 128 + c];
            WT2[c * 512 + s] = f2b(v);
        }
    } else if (b < 9052) {                       // zero counters region: 250002 ints
        int i = (b - 8075) * 256 + t;
        if (i < 250002) zero_region[i] = 0;
    } else {                                     // zero mark[NN]
        int i = (b - 9052) * 256 + t;
        if (i < NN) mark[i] = 0;
    }
}

// ---------------- CSR hist + idx mark/compact ----------------

__global__ void k_hist_mark(const int* __restrict__ ei, const int* __restrict__ et,
                            int* __restrict__ deg_node, int* __restrict__ deg_rel,
                            const int* __restrict__ idx, int* __restrict__ mark,
                            int* __restrict__ cnt2, int* __restrict__ list) {
    int b = blockIdx.x;
    if (b < 2344) {
        int e = b * 256 + threadIdx.x;
        if (e < NE) {
            int dst = ei[NE + e];
            int r = et[e];
            atomicAdd(&deg_node[dst], 1);
            atomicAdd(&deg_rel[r * NN + dst], 1);
        }
    } else {
        int i = (b - 2344) * 256 + threadIdx.x;
        if (i < NIDX) {
            int n = idx[i];
            if (atomicExch(&mark[n], 1) == 0) {
                int p = atomicAdd(cnt2, 1);
                list[p] = n;
            }
        }
    }
}

// ---------------- alloc (CSR offsets) + norm ----------------

__global__ void k_alloc_norm(const int* __restrict__ deg_node, int* __restrict__ baseoff,
                             int* __restrict__ counter, const int* __restrict__ deg_rel,
                             float* __restrict__ normf) {
    int b = blockIdx.x;
    if (b < 196) {
        int i = b * 256 + threadIdx.x;
        int lane = threadIdx.x & 63;
        int d = (i < NN) ? deg_node[i] : 0;
        int scan = d;
        for (int off = 1; off < 64; off <<= 1) {
            int t = __shfl_up(scan, off, 64);
            if (lane >= off) scan += t;
        }
        int total = __shfl(scan, 63, 64);
        int wbase = 0;
        if (lane == 63) wbase = atomicAdd(counter, total);
        wbase = __shfl(wbase, 63, 64);
        if (i < NN) baseoff[i] = wbase + scan - d;
    } else {
        int i = (b - 196) * 256 + threadIdx.x;
        if (i < 3 * NN) normf[i] = 1.0f / (float)max(deg_rel[i], 1);
    }
}

__global__ void k_fill(const int* __restrict__ ei, const int* __restrict__ et,
                       const int* __restrict__ baseoff, int* __restrict__ cursor,
                       int* __restrict__ elist) {
    int e = blockIdx.x * 256 + threadIdx.x;
    if (e >= NE) return;
    int dst = ei[NE + e];
    int src = ei[e];
    int r = et[e];
    int pos = atomicAdd(&cursor[dst], 1);
    elist[baseoff[dst] + pos] = src | (r << 20);
}

// ---------------- aggregation (round-11 serial form, measured best) ----------------

__global__ __launch_bounds__(64) void k_agg(const u16* __restrict__ x, u16* __restrict__ A,
                                            const int* __restrict__ elist,
                                            const int* __restrict__ baseoff,
                                            const int* __restrict__ deg_node,
                                            const float* __restrict__ normf) {
    int n = blockIdx.x;
    int lane = threadIdx.x;
    float a0x = 0.f, a0y = 0.f, a1x = 0.f, a1y = 0.f, a2x = 0.f, a2y = 0.f;
    int nb = deg_node[n];
    int b0 = baseoff[n];
    for (int i = 0; i < nb; ++i) {
        int p = elist[b0 + i];
        int src = p & 0xFFFFF;
        int r = p >> 20;
        u32 pair = *(const u32*)&x[(size_t)src * 128 + lane * 2];
        float vx = __uint_as_float((pair & 0xFFFFu) << 16);
        float vy = __uint_as_float((pair >> 16) << 16);
        if (r == 0)      { a0x += vx; a0y += vy; }
        else if (r == 1) { a1x += vx; a1y += vy; }
        else             { a2x += vx; a2y += vy; }
    }
    float n0 = normf[n], n1 = normf[NN + n], n2 = normf[2 * NN + n];
    u32* Ao = (u32*)&A[(size_t)n * 384];
    Ao[lane]        = (u32)f2b(a0x * n0) | ((u32)f2b(a0y * n0) << 16);
    Ao[64 + lane]   = (u32)f2b(a1x * n1) | ((u32)f2b(a1y * n1) << 16);
    Ao[128 + lane]  = (u32)f2b(a2x * n2) | ((u32)f2b(a2y * n2) << 16);
}

// layer-2 aggregation: only rows in list[0..cnt2), output compacted
__global__ __launch_bounds__(64) void k_agg2(const u16* __restrict__ x, u16* __restrict__ A2buf,
                                             const int* __restrict__ elist,
                                             const int* __restrict__ baseoff,
                                             const int* __restrict__ deg_node,
                                             const float* __restrict__ normf,
                                             const int* __restrict__ list,
                                             const int* __restrict__ cnt2) {
    int i = blockIdx.x;
    if (i >= *cnt2) return;
    int n = list[i];
    int lane = threadIdx.x;
    float a0x = 0.f, a0y = 0.f, a1x = 0.f, a1y = 0.f, a2x = 0.f, a2y = 0.f;
    int nb = deg_node[n];
    int b0 = baseoff[n];
    for (int e = 0; e < nb; ++e) {
        int p = elist[b0 + e];
        int src = p & 0xFFFFF;
        int r = p >> 20;
        u32 pair = *(const u32*)&x[(size_t)src * 128 + lane * 2];
        float vx = __uint_as_float((pair & 0xFFFFu) << 16);
        float vy = __uint_as_float((pair >> 16) << 16);
        if (r == 0)      { a0x += vx; a0y += vy; }
        else if (r == 1) { a1x += vx; a1y += vy; }
        else             { a2x += vx; a2y += vy; }
    }
    float n0 = normf[n], n1 = normf[NN + n], n2 = normf[2 * NN + n];
    u32* Ao = (u32*)&A2buf[(size_t)i * 384];
    Ao[lane]        = (u32)f2b(a0x * n0) | ((u32)f2b(a0y * n0) << 16);
    Ao[64 + lane]   = (u32)f2b(a1x * n1) | ((u32)f2b(a1y * n1) << 16);
    Ao[128 + lane]  = (u32)f2b(a2x * n2) | ((u32)f2b(a2y * n2) << 16);
}

// ---------------- GEMM body (round-11): BM=64, 3 LDS buffers, depth-2,
// counted vmcnt at no-drain barriers. LIST mode: dynamic N=*cntp, A2 and
// output rows indirected through list[] ----------------

template <typename TA, int K1T, int K2T, bool LRELU, bool LIST>
__device__ __forceinline__ void gemm_body(const TA* __restrict__ A1, int lda1,
                                          const TA* __restrict__ A2, int lda2,
                                          const u16* __restrict__ WT, int ldwt,
                                          const float* __restrict__ bias,
                                          u16* __restrict__ out, int Nin,
                                          const int* __restrict__ list,
                                          const int* __restrict__ cntp) {
    constexpr int KT = K1T + K2T;
    constexpr int ABYTES = 64 * 32 * (int)sizeof(TA);
    constexpr int TILEB = ABYTES + 8192;
    constexpr int OPW = (sizeof(TA) == 4) ? 4 : 3;   // DMA instrs per wave per stage
    __shared__ alignas(128) char lds[3][TILEB];

    const int N = LIST ? *cntp : Nin;
    const int m0 = blockIdx.x * 64;
    if (LIST && m0 >= N) return;   // uniform whole-block exit, before any barrier

    const int tid = threadIdx.x;
    const int w = tid >> 6, lane = tid & 63;
    const int wr = w >> 1, wc = w & 1;
    const int lq = lane >> 4, lr = lane & 15;

    auto stage = [&](int j) {
        char* base = lds[j % 3];
        int kt = j;
        if constexpr (sizeof(TA) == 4) {
#pragma unroll
            for (int jj = 0; jj < 2; ++jj) {
                int row = w * 16 + jj * 8 + (lane >> 3);
                int s = lane & 7;
                int chunk = s ^ (row & 7);
                int rg = min(m0 + row, N - 1);
                const float* g;
                if (kt < K1T) g = (const float*)A1 + (size_t)rg * lda1 + kt * 32 + chunk * 4;
                else          g = (const float*)A2 + (size_t)rg * lda2 + (kt - K1T) * 32 + chunk * 4;
                gl_lds16(g, base + w * 2048 + jj * 1024);
            }
        } else {
            int row = w * 16 + (lane >> 2);
            int s = lane & 3;
            int chunk = s ^ ((row >> 1) & 3);
            int rg = min(m0 + row, N - 1);
            const u16* g;
            if (kt < K1T) {
                g = (const u16*)A1 + (size_t)rg * lda1 + kt * 32 + chunk * 8;
            } else {
                int node = LIST ? list[rg] : rg;
                g = (const u16*)A2 + (size_t)node * lda2 + (kt - K1T) * 32 + chunk * 8;
            }
            gl_lds16(g, base + w * 1024);
        }
#pragma unroll
        for (int jj = 0; jj < 2; ++jj) {
            int col = w * 32 + jj * 16 + (lane >> 2);
            int s = lane & 3;
            int chunk = s ^ ((col >> 1) & 3);
            const u16* g = WT + (size_t)col * ldwt + kt * 32 + chunk * 8;
            gl_lds16(g, base + ABYTES + w * 2048 + jj * 1024);
        }
    };

    f32x4 acc[2][4] = {};

    auto compute = [&](int j) {
        char* base = lds[j % 3];
        s16x8 af[2];
#pragma unroll
        for (int i = 0; i < 2; ++i) {
            int row = wr * 32 + i * 16 + lr;
            if constexpr (sizeof(TA) == 4) {
                int m = row & 7;
                float4 f0 = *(const float4*)(base + row * 128 + (((2 * lq) ^ m) * 16));
                float4 f1 = *(const float4*)(base + row * 128 + (((2 * lq + 1) ^ m) * 16));
                af[i] = pack8(f0, f1);
            } else {
                int sl = lq ^ ((row >> 1) & 3);
                af[i] = *(const s16x8*)(base + row * 64 + sl * 16);
            }
        }
#pragma unroll
        for (int j4 = 0; j4 < 4; ++j4) {
            int col = wc * 64 + j4 * 16 + lr;
            int sl = lq ^ ((col >> 1) & 3);
            s16x8 bf = *(const s16x8*)(base + ABYTES + col * 64 + sl * 16);
#pragma unroll
            for (int i = 0; i < 2; ++i)
                acc[i][j4] = __builtin_amdgcn_mfma_f32_16x16x32_bf16(af[i], bf, acc[i][j4], 0, 0, 0);
        }
    };

    stage(0); stage(1);
#pragma unroll 1
    for (int j = 0; j < KT - 1; ++j) {
        vmwait<OPW>();
        barrier_nodrains();
        if (j + 2 < KT) stage(j + 2);
        compute(j);
    }
    vmwait<0>();
    barrier_nodrains();
    compute(KT - 1);

#pragma unroll
    for (int i = 0; i < 2; ++i) {
#pragma unroll
        for (int q = 0; q < 4; ++q) {
            int grow = m0 + wr * 32 + i * 16 + lq * 4 + q;
            if (grow < N) {
                int orow = LIST ? list[grow] : grow;
#pragma unroll
                for (int j = 0; j < 4; ++j) {
                    int col = wc * 64 + j * 16 + lr;
                    float v = acc[i][j][q] + bias[col];
                    if (LRELU) v = v > 0.f ? v : 0.01f * v;
                    out[(size_t)orow * 128 + col] = f2b(v);
                }
            }
        }
    }
}

__global__ __launch_bounds__(256) void k_gemm_in(const float* __restrict__ A1, int lda1,
                                                 const float* __restrict__ A2, int lda2,
                                                 const u16* __restrict__ WT, int ldwt,
                                                 const float* __restrict__ bias,
                                                 u16* __restrict__ out, int N) {
    gemm_body<float, 24, 1, true, false>(A1, lda1, A2, lda2, WT, ldwt, bias, out, N, nullptr, nullptr);
}
__global__ __launch_bounds__(256) void k_gemm_r1(const u16* __restrict__ A1, int lda1,
                                                 const u16* __restrict__ A2, int lda2,
                                                 const u16* __restrict__ WT, int ldwt,
                                                 const float* __restrict__ bias,
                                                 u16* __restrict__ out, int N) {
    gemm_body<u16, 12, 4, false, false>(A1, lda1, A2, lda2, WT, ldwt, bias, out, N, nullptr, nullptr);
}
__global__ __launch_bounds__(256) void k_gemm_r2(const u16* __restrict__ A1, int lda1,
                                                 const u16* __restrict__ A2, int lda2,
                                                 const u16* __restrict__ WT, int ldwt,
                                                 const float* __restrict__ bias,
                                                 u16* __restrict__ out,
                                                 const int* __restrict__ list,
                                                 const int* __restrict__ cnt2) {
    gemm_body<u16, 12, 4, false, true>(A1, lda1, A2, lda2, WT, ldwt, bias, out, NIDX, list, cnt2);
}

// ---------------- final gather + classifier ----------------

__global__ __launch_bounds__(256) void k_out(const u16* __restrict__ h, const int* __restrict__ idx,
                                             const float* __restrict__ fc3w,
                                             const float* __restrict__ fc3b,
                                             float* __restrict__ out, int M) {
    int w = threadIdx.x >> 6;
    int lane = threadIdx.x & 63;
    int row = blockIdx.x * 4 + w;
    if (row >= M) return;
    int n = idx[row];
    u32 pair = *(const u32*)&h[(size_t)n * 128 + lane * 2];
    float v0 = __uint_as_float((pair & 0xFFFFu) << 16);
    float v1 = __uint_as_float((pair >> 16) << 16);
    float4 wv = *(const float4*)&fc3w[lane * 4];
    float s0 = v0 * wv.x + v1 * wv.z;
    float s1 = v0 * wv.y + v1 * wv.w;
    for (int off = 32; off >= 1; off >>= 1) {
        s0 += __shfl_xor(s0, off, 64);
        s1 += __shfl_xor(s1, off, 64);
    }
    if (lane == 0) {
        out[row * 2] = s0 + fc3b[0];
        out[row * 2 + 1] = s1 + fc3b[1];
    }
}

// ---------------- launch ----------------

extern "C" void kernel_launch(void* const* d_in, const int* in_sizes, int n_in,
                              void* d_out, int out_size, void* d_ws, size_t ws_size,
                              hipStream_t stream) {
    const float* vf    = (const float*)d_in[0];
    const float* tf    = (const float*)d_in[1];
    const float* fc1w  = (const float*)d_in[2];
    const float* fc1b  = (const float*)d_in[3];
    const float* fc2w  = (const float*)d_in[4];
    const float* fc2b  = (const float*)d_in[5];
    const float* reluw = (const float*)d_in[6];
    const float* relub = (const float*)d_in[7];
    const float* w1rel = (const float*)d_in[8];
    const float* w1root= (const float*)d_in[9];
    const float* b1    = (const float*)d_in[10];
    const float* w2rel = (const float*)d_in[11];
    const float* w2root= (const float*)d_in[12];
    const float* b2    = (const float*)d_in[13];
    const float* fc3w  = (const float*)d_in[14];
    const float* fc3b  = (const float*)d_in[15];
    const int* ei      = (const int*)d_in[16];
    const int* et      = (const int*)d_in[17];
    const int* idx     = (const int*)d_in[18];
    float* out = (float*)d_out;

    char* W = (char*)d_ws;
    const size_t OFF_WTIN  = 0;         // 204800
    const size_t OFF_WT1   = 204800;    // 131072
    const size_t OFF_WT2   = 335872;    // 131072
    const size_t OFF_BCOMB = 466944;    // 512
    const size_t OFF_DEGN  = 467456;    // zero region start: degn(200000) cur(200000) degr(600000) cnt(4) cnt2(4) = 250002 ints
    const size_t OFF_CUR   = 667456;
    const size_t OFF_DEGR  = 867456;
    const size_t OFF_CNT   = 1467456;
    const size_t OFF_CNT2  = 1467460;
    const size_t OFF_BASE  = 1467712;
    const size_t OFF_NORM  = 1667712;
    const size_t OFF_ELIST = 2267712;
    const size_t OFF_A     = 4667712;
    const size_t OFF_H0    = 43067712;
    const size_t OFF_H1    = 55867712;
    const size_t OFF_H2    = 68667712;
    const size_t OFF_VFPAD = 81467712;  // 6400000
    const size_t OFF_LIST  = 87867712;  // 40000
    const size_t OFF_A2    = 87907712;  // 7680000
    const size_t OFF_MARK  = 95587712;  // 200000 -> total 95787712

    u16* WTin   = (u16*)(W + OFF_WTIN);
    u16* WT1    = (u16*)(W + OFF_WT1);
    u16* WT2    = (u16*)(W + OFF_WT2);
    float* bcomb= (float*)(W + OFF_BCOMB);
    int* degn   = (int*)(W + OFF_DEGN);
    int* cur    = (int*)(W + OFF_CUR);
    int* degr   = (int*)(W + OFF_DEGR);
    int* cnt    = (int*)(W + OFF_CNT);
    int* cnt2   = (int*)(W + OFF_CNT2);
    int* base   = (int*)(W + OFF_BASE);
    float* normf= (float*)(W + OFF_NORM);
    int* elist  = (int*)(W + OFF_ELIST);
    u16* Abuf   = (u16*)(W + OFF_A);
    u16* h0     = (u16*)(W + OFF_H0);
    u16* h1     = (u16*)(W + OFF_H1);
    u16* h2     = (u16*)(W + OFF_H2);
    float* vfp  = (float*)(W + OFF_VFPAD);
    int* list   = (int*)(W + OFF_LIST);
    u16* A2buf  = (u16*)(W + OFF_A2);
    int* mark   = (int*)(W + OFF_MARK);

    const int GRID_GEMM = (NN + 63) / 64;      // 782
    const int GRID_G2   = (NIDX + 63) / 64;    // 157

    // 1. fused setup (padvf | win | bcomb | wrg1 | wrg2 | zero counters | zero mark)
    k_setup<<<9248, 256, 0, stream>>>(vf, fc1w, fc2w, reluw, fc1b, fc2b, relub,
                                      w1rel, w1root, w2rel, w2root,
                                      vfp, WTin, bcomb, WT1, WT2, degn, mark);

    // 2. fused input GEMM
    k_gemm_in<<<GRID_GEMM, 256, 0, stream>>>(tf, 768, vfp, 32, WTin, 800, bcomb, h0, NN);

    // 3. CSR build + idx mark/compact
    k_hist_mark<<<2384, 256, 0, stream>>>(ei, et, degn, degr, idx, mark, cnt2, list);
    k_alloc_norm<<<782, 256, 0, stream>>>(degn, base, cnt, degr, normf);
    k_fill<<<(NE + 255) / 256, 256, 0, stream>>>(ei, et, base, cur, elist);

    // 4. RGCN layer 1 (full)
    k_agg<<<NN, 64, 0, stream>>>(h0, Abuf, elist, base, degn, normf);
    k_gemm_r1<<<GRID_GEMM, 256, 0, stream>>>(Abuf, 384, h0, 128, WT1, 512, b1, h1, NN);

    // 5. RGCN layer 2 (only idx rows: list[0..cnt2))
    k_agg2<<<NIDX, 64, 0, stream>>>(h1, A2buf, elist, base, degn, normf, list, cnt2);
    k_gemm_r2<<<GRID_G2, 256, 0, stream>>>(A2buf, 384, h1, 128, WT2, 512, b2, h2, list, cnt2);

    // 6. classifier on gathered rows
    k_out<<<(NIDX + 3) / 4, 256, 0, stream>>>(h2, idx, fc3w, fc3b, out, NIDX);
}